// Round 11
// baseline (199.604 us; speedup 1.0000x reference)
//
#include <hip/hip_runtime.h>
#include <hip/hip_bf16.h>
#include <stdint.h>

typedef __attribute__((ext_vector_type(8))) short short8;
typedef __attribute__((ext_vector_type(4))) float floatx4;

#define MFMA16(a, b, c) __builtin_amdgcn_mfma_f32_16x16x32_bf16((a), (b), (c), 0, 0, 0)

static __device__ __forceinline__ uint16_t f2bf(float f) {
  union { float f; uint32_t u; } x; x.f = f;
  uint32_t r = x.u + 0x7fffu + ((x.u >> 16) & 1u);
  return (uint16_t)(r >> 16);
}

static __device__ __forceinline__ uint32_t cvtpk_bf16(float lo, float hi) {
  uint32_t r;
  asm("v_cvt_pk_bf16_f32 %0, %1, %2" : "=v"(r) : "v"(lo), "v"(hi));
  return r;
}

constexpr int DM = 1024, NH = 16, KD = 64, NB = 2, SQ = 2048;
constexpr int MTOT = NB * SQ;  // 4096
constexpr int NT = SQ / 64;    // 32 kv tiles
constexpr int NP = NT / 2;     // 16 kv pairs

// ---------------- kernel 1: fp32 -> bf16 convert ----------------
__global__ void convert_kernel(const float* __restrict__ X,
                               const float* __restrict__ Wq, const float* __restrict__ Wk,
                               const float* __restrict__ Wv, const float* __restrict__ Wo,
                               uint16_t* __restrict__ Xb, uint16_t* __restrict__ Wqkvb,
                               uint16_t* __restrict__ Wob) {
  const int NX = MTOT * DM;   // 4194304
  const int NW = DM * DM;     // 1048576
  const int TOT8 = (NX + 4 * NW) / 8;
  for (int t = blockIdx.x * blockDim.x + threadIdx.x; t < TOT8; t += gridDim.x * blockDim.x) {
    int i = t * 8;
    const float* src; uint16_t* dst;
    if (i < NX) { src = X + i; dst = Xb + i; }
    else if (i < NX + 3 * NW) {
      int j = i - NX; dst = Wqkvb + j;
      src = (j < NW) ? (Wq + j) : (j < 2 * NW) ? (Wk + (j - NW)) : (Wv + (j - 2 * NW));
    } else {
      int j = i - NX - 3 * NW; src = Wo + j; dst = Wob + j;
    }
    float4 a = ((const float4*)src)[0];
    float4 b = ((const float4*)src)[1];
    ushort4 o0, o1;
    o0.x = f2bf(a.x); o0.y = f2bf(a.y); o0.z = f2bf(a.z); o0.w = f2bf(a.w);
    o1.x = f2bf(b.x); o1.y = f2bf(b.y); o1.z = f2bf(b.z); o1.w = f2bf(b.w);
    ((ushort4*)dst)[0] = o0;
    ((ushort4*)dst)[1] = o1;
  }
}

// ---------------- kernel 2: 128x128 bf16 GEMM, BK=64 + XOR-swizzled LDS (QKV) ----------------
// Staging: linear LDS dest (G21) + pre-swizzled GLOBAL source col ((lane&7)^(lane>>3)) so that
// LDS slot' = slot ^ (row&7). Fragment reads apply the same XOR -> bank-conflict-free.
__global__ __launch_bounds__(256) void gemm_qkv(const uint16_t* __restrict__ Aq,
                                                const uint16_t* __restrict__ Bq,
                                                uint16_t* __restrict__ Qb, uint16_t* __restrict__ Kb,
                                                uint16_t* __restrict__ VTb) {
  __shared__ uint16_t Al[128 * 64];   // 16KB
  __shared__ uint16_t Bl[128 * 64];   // 16KB
  const int K = 1024;
  const int Ntiles = 24;
  int nwg = gridDim.x;
  int bid = (blockIdx.x & 7) * (nwg >> 3) + (blockIdx.x >> 3);
  int bm = bid / Ntiles, bn = bid % Ntiles;
  int brow = bm * 128, bcol = bn * 128;
  int tid = threadIdx.x;
  int w = tid >> 6, lane = tid & 63, g = lane >> 4, c16 = lane & 15;
  int wm = w >> 1, wn = w & 1;
  int rr = tid >> 3;                       // 0..31: row within 32-row round
  int ces = ((tid & 7) ^ (rr & 7)) * 8;    // swizzled source col element (stays in same 128B line)

  floatx4 acc[4][4] = {};

  for (int k0 = 0; k0 < K; k0 += 64) {
    __syncthreads();
#pragma unroll
    for (int i = 0; i < 4; ++i) {
      __builtin_amdgcn_global_load_lds(
          (const __attribute__((address_space(1))) void*)(Aq + (size_t)(brow + i * 32 + rr) * K + k0 + ces),
          (__attribute__((address_space(3))) void*)((char*)Al + i * 4096 + w * 1024), 16, 0, 0);
      __builtin_amdgcn_global_load_lds(
          (const __attribute__((address_space(1))) void*)(Bq + (size_t)(bcol + i * 32 + rr) * K + k0 + ces),
          (__attribute__((address_space(3))) void*)((char*)Bl + i * 4096 + w * 1024), 16, 0, 0);
    }
    __syncthreads();
#pragma unroll
    for (int kk = 0; kk < 2; ++kk) {
      short8 af[4], bf[4];
#pragma unroll
      for (int mt = 0; mt < 4; ++mt)
        af[mt] = *(const short8*)((const char*)Al + (wm * 64 + mt * 16 + c16) * 128 +
                                  (((kk * 4 + g) ^ (c16 & 7)) << 4));
#pragma unroll
      for (int nt = 0; nt < 4; ++nt)
        bf[nt] = *(const short8*)((const char*)Bl + (wn * 64 + nt * 16 + c16) * 128 +
                                  (((kk * 4 + g) ^ (c16 & 7)) << 4));
#pragma unroll
      for (int mt = 0; mt < 4; ++mt)
#pragma unroll
        for (int nt = 0; nt < 4; ++nt)
          acc[mt][nt] = MFMA16(af[mt], bf[nt], acc[mt][nt]);
    }
  }

#pragma unroll
  for (int mt = 0; mt < 4; ++mt) {
#pragma unroll
    for (int nt = 0; nt < 4; ++nt) {
      int n = bcol + wn * 64 + nt * 16 + c16;
#pragma unroll
      for (int r = 0; r < 4; ++r) {
        int m = brow + wm * 64 + mt * 16 + g * 4 + r;
        float v = acc[mt][nt][r];
        int proj = n >> 10;
        int hd = n & 1023;
        int h = hd >> 6, d = hd & 63;
        int b = m >> 11, s = m & 2047;
        size_t bh = (size_t)(b * NH + h);
        if (proj == 0) {
          // fold 1/sqrt(64) * log2(e) so attention can use exp2 directly
          Qb[(bh * SQ + s) * KD + d] = f2bf(v * 0.18033688011112042f);
        } else if (proj == 1) {
          // K blocked frag-linear: elem = st*1024 + k8*128 + r2*8 + j
          int st = s >> 4, r2 = s & 15, k8 = d >> 3, j = d & 7;
          Kb[bh * (size_t)(SQ * KD) + (((size_t)(st * 8 + k8) * 16 + r2) * 8 + j)] = f2bf(v);
        } else {
          // V pi-permuted blocked per 64-kv tile
          int kt = s >> 6, kvl = s & 63;
          int c = kvl >> 5, tth = (kvl >> 4) & 1, gg = (kvl >> 2) & 3, rs = kvl & 3;
          int jp = tth * 4 + rs;
          int dt = d >> 4, cc = d & 15;
          VTb[bh * (size_t)(SQ * KD) + (size_t)kt * 4096 +
              (size_t)((c * 4 + dt) * 512 + gg * 128 + cc * 8 + jp)] = f2bf(v);
        }
      }
    }
  }
}

// ---------------- kernel 4: 64x128 bf16 GEMM, BK=64 + XOR swizzle (fp32 out) ----------------
__global__ __launch_bounds__(256) void gemm_out64(const uint16_t* __restrict__ Aq,
                                                  const uint16_t* __restrict__ Bq,
                                                  float* __restrict__ Out) {
  __shared__ uint16_t Al[64 * 64];    // 8KB
  __shared__ uint16_t Bl[128 * 64];   // 16KB
  const int K = 1024;
  int nwg = gridDim.x;  // 512
  int bid = (blockIdx.x & 7) * (nwg >> 3) + (blockIdx.x >> 3);
  int bm = bid >> 3, bn = bid & 7;   // 64 x 8 tiles
  int brow = bm * 64, bcol = bn * 128;
  int tid = threadIdx.x;
  int w = tid >> 6, lane = tid & 63, g = lane >> 4, c16 = lane & 15;
  int wm = w >> 1, wn = w & 1;       // wave-tile: 32 rows x 64 cols
  int rr = tid >> 3;                 // 0..31
  int ces = ((tid & 7) ^ (rr & 7)) * 8;

  floatx4 acc[2][4] = {};

  for (int k0 = 0; k0 < K; k0 += 64) {
    __syncthreads();
#pragma unroll
    for (int i = 0; i < 2; ++i)
      __builtin_amdgcn_global_load_lds(
          (const __attribute__((address_space(1))) void*)(Aq + (size_t)(brow + i * 32 + rr) * K + k0 + ces),
          (__attribute__((address_space(3))) void*)((char*)Al + i * 4096 + w * 1024), 16, 0, 0);
#pragma unroll
    for (int i = 0; i < 4; ++i)
      __builtin_amdgcn_global_load_lds(
          (const __attribute__((address_space(1))) void*)(Bq + (size_t)(bcol + i * 32 + rr) * K + k0 + ces),
          (__attribute__((address_space(3))) void*)((char*)Bl + i * 4096 + w * 1024), 16, 0, 0);
    __syncthreads();
#pragma unroll
    for (int kk = 0; kk < 2; ++kk) {
      short8 af[2], bf[4];
#pragma unroll
      for (int mt = 0; mt < 2; ++mt)
        af[mt] = *(const short8*)((const char*)Al + (wm * 32 + mt * 16 + c16) * 128 +
                                  (((kk * 4 + g) ^ (c16 & 7)) << 4));
#pragma unroll
      for (int nt = 0; nt < 4; ++nt)
        bf[nt] = *(const short8*)((const char*)Bl + (wn * 64 + nt * 16 + c16) * 128 +
                                  (((kk * 4 + g) ^ (c16 & 7)) << 4));
#pragma unroll
      for (int mt = 0; mt < 2; ++mt)
#pragma unroll
        for (int nt = 0; nt < 4; ++nt)
          acc[mt][nt] = MFMA16(af[mt], bf[nt], acc[mt][nt]);
    }
  }

#pragma unroll
  for (int mt = 0; mt < 2; ++mt) {
#pragma unroll
    for (int nt = 0; nt < 4; ++nt) {
      int n = bcol + wn * 64 + nt * 16 + c16;
#pragma unroll
      for (int r = 0; r < 4; ++r) {
        int m = brow + wm * 32 + mt * 16 + g * 4 + r;
        Out[(size_t)m * DM + n] = acc[mt][nt][r];
      }
    }
  }
}

// ---------------- kernel 3: flash attention (UNCHANGED from R10 — control) ----------------
__global__ __launch_bounds__(512, 4) void attn_kernel(const uint16_t* __restrict__ Q,
                                                      const uint16_t* __restrict__ Kt,
                                                      const uint16_t* __restrict__ Vt,
                                                      uint16_t* __restrict__ O) {
  __shared__ __attribute__((aligned(16))) uint16_t Kbuf[2][8192];  // 2 x 16KB (tile pair)
  __shared__ __attribute__((aligned(16))) uint16_t Vbuf[2][8192];  // 2 x 16KB

  int bid = blockIdx.x;
  int bh = bid & 31, qt = bid >> 5;    // 32 bh x 16 q-tiles = 512 blocks
  int qb = qt * 128;
  int b = bh >> 4, h = bh & 15;
  int tid = threadIdx.x, lane = tid & 63, wv = tid >> 6, g = lane >> 4, c16 = lane & 15;

  const uint16_t* Qh = Q + (size_t)bh * SQ * KD;
  const uint16_t* Kh = Kt + (size_t)bh * SQ * KD;
  const uint16_t* Vh = Vt + (size_t)bh * SQ * KD;

  int qrow = qb + wv * 16 + c16;
  short8 qf0 = *(const short8*)&Qh[(size_t)qrow * KD + g * 8];
  short8 qf1 = *(const short8*)&Qh[(size_t)qrow * KD + 32 + g * 8];

  float l = 0.0f;               // per-lane PARTIAL sum; reduced once at the end
  floatx4 accO[4] = {};
  const floatx4 SHIFT_INIT = {-16.0f, -16.0f, -16.0f, -16.0f};

  auto stage = [&](int buf, int pair) {
    size_t base = (size_t)pair * 8192;
#pragma unroll
    for (int i = 0; i < 2; ++i) {
      __builtin_amdgcn_global_load_lds(
          (const __attribute__((address_space(1))) void*)(Kh + base + wv * 1024 + i * 512 + lane * 8),
          (__attribute__((address_space(3))) void*)((char*)&Kbuf[buf][0] + wv * 2048 + i * 1024), 16, 0, 0);
      __builtin_amdgcn_global_load_lds(
          (const __attribute__((address_space(1))) void*)(Vh + base + wv * 1024 + i * 512 + lane * 8),
          (__attribute__((address_space(3))) void*)((char*)&Vbuf[buf][0] + wv * 2048 + i * 1024), 16, 0, 0);
    }
  };

  stage(0, 0);
  __syncthreads();

  for (int p = 0; p < NP; ++p) {
    int cur = p & 1;
    int pn = (p + 1 < NP) ? (p + 1) : p;
    stage(cur ^ 1, pn);

#pragma unroll
    for (int sub = 0; sub < 2; ++sub) {
      const char* kb = (const char*)&Kbuf[cur][sub * 4096];
      const char* vb = (const char*)&Vbuf[cur][sub * 4096];
      short8 kf[4][2], vf[2][4];
#pragma unroll
      for (int tt = 0; tt < 4; ++tt)
#pragma unroll
        for (int hf = 0; hf < 2; ++hf)
          kf[tt][hf] = *(const short8*)(kb + tt * 2048 + hf * 1024 + lane * 16);
#pragma unroll
      for (int c = 0; c < 2; ++c)
#pragma unroll
        for (int dt = 0; dt < 4; ++dt)
          vf[c][dt] = *(const short8*)(vb + (c * 4 + dt) * 1024 + lane * 16);

      floatx4 sacc[4];
#pragma unroll
      for (int tt = 0; tt < 4; ++tt) sacc[tt] = SHIFT_INIT;
      __builtin_amdgcn_s_setprio(1);
#pragma unroll
      for (int tt = 0; tt < 4; ++tt) {
        sacc[tt] = MFMA16(kf[tt][0], qf0, sacc[tt]);
        sacc[tt] = MFMA16(kf[tt][1], qf1, sacc[tt]);
      }
      __builtin_amdgcn_s_setprio(0);

#pragma unroll
      for (int tt = 0; tt < 4; ++tt)
#pragma unroll
        for (int r = 0; r < 4; ++r)
          sacc[tt][r] = exp2f(sacc[tt][r]);
      float s01 = (sacc[0][0] + sacc[0][1]) + (sacc[0][2] + sacc[0][3]);
      float s23 = (sacc[1][0] + sacc[1][1]) + (sacc[1][2] + sacc[1][3]);
      float s45 = (sacc[2][0] + sacc[2][1]) + (sacc[2][2] + sacc[2][3]);
      float s67 = (sacc[3][0] + sacc[3][1]) + (sacc[3][2] + sacc[3][3]);
      l += (s01 + s23) + (s45 + s67);

      union { uint32_t u[4]; short8 s8; } pa[2];
#pragma unroll
      for (int c = 0; c < 2; ++c) {
        pa[c].u[0] = cvtpk_bf16(sacc[2 * c][0], sacc[2 * c][1]);
        pa[c].u[1] = cvtpk_bf16(sacc[2 * c][2], sacc[2 * c][3]);
        pa[c].u[2] = cvtpk_bf16(sacc[2 * c + 1][0], sacc[2 * c + 1][1]);
        pa[c].u[3] = cvtpk_bf16(sacc[2 * c + 1][2], sacc[2 * c + 1][3]);
      }
      __builtin_amdgcn_s_setprio(1);
#pragma unroll
      for (int c = 0; c < 2; ++c)
#pragma unroll
        for (int dt = 0; dt < 4; ++dt)
          accO[dt] = MFMA16(pa[c].s8, vf[c][dt], accO[dt]);
      __builtin_amdgcn_s_setprio(0);
    }

    __syncthreads();
  }

  l += __shfl_xor(l, 16);
  l += __shfl_xor(l, 32);

  float lv[4];
#pragma unroll
  for (int r = 0; r < 4; ++r) lv[r] = 1.0f / __shfl(l, g * 4 + r);
#pragma unroll
  for (int dt = 0; dt < 4; ++dt) {
#pragma unroll
    for (int r = 0; r < 4; ++r) {
      int s = qb + wv * 16 + g * 4 + r;
      int d = dt * 16 + c16;
      O[((size_t)(b * SQ + s)) * DM + h * KD + d] = f2bf(accO[dt][r] * lv[r]);
    }
  }
}

// ---------------- launch ----------------
extern "C" void kernel_launch(void* const* d_in, const int* in_sizes, int n_in,
                              void* d_out, int out_size, void* d_ws, size_t ws_size,
                              hipStream_t stream) {
  const float* X = (const float*)d_in[0];
  const float* Wq = (const float*)d_in[1];
  const float* Wk = (const float*)d_in[2];
  const float* Wv = (const float*)d_in[3];
  const float* Wo = (const float*)d_in[4];
  float* out = (float*)d_out;

  char* ws = (char*)d_ws;
  uint16_t* Xb    = (uint16_t*)(ws);                 //  8 MiB  [4096][1024]
  uint16_t* Wqkvb = (uint16_t*)(ws + 8388608);       //  6 MiB  [3072][1024]
  uint16_t* Wob   = (uint16_t*)(ws + 14680064);      //  2 MiB  [1024][1024]
  uint16_t* Qb    = (uint16_t*)(ws + 16777216);      //  8 MiB  (bh,s,d)
  uint16_t* Kb    = (uint16_t*)(ws + 25165824);      //  8 MiB  blocked
  uint16_t* VTb   = (uint16_t*)(ws + 33554432);      //  8 MiB  pi-permuted blocked
  uint16_t* Ob    = (uint16_t*)(ws + 41943040);      //  8 MiB  [4096][1024]

  hipLaunchKernelGGL(convert_kernel, dim3(1024), dim3(256), 0, stream,
                     X, Wq, Wk, Wv, Wo, Xb, Wqkvb, Wob);
  hipLaunchKernelGGL(gemm_qkv, dim3(32 * 24), dim3(256), 0, stream,
                     Xb, Wqkvb, Qb, Kb, VTb);
  hipLaunchKernelGGL(attn_kernel, dim3(512), dim3(512), 0, stream,
                     Qb, Kb, VTb, Ob);
  hipLaunchKernelGGL(gemm_out64, dim3(512), dim3(256), 0, stream,
                     Ob, Wob, out);
}

// Round 12
// 190.590 us; speedup vs baseline: 1.0473x; 1.0473x over previous
//
#include <hip/hip_runtime.h>
#include <hip/hip_bf16.h>
#include <stdint.h>

typedef __attribute__((ext_vector_type(8))) short short8;
typedef __attribute__((ext_vector_type(4))) float floatx4;

#define MFMA16(a, b, c) __builtin_amdgcn_mfma_f32_16x16x32_bf16((a), (b), (c), 0, 0, 0)

static __device__ __forceinline__ uint16_t f2bf(float f) {
  union { float f; uint32_t u; } x; x.f = f;
  uint32_t r = x.u + 0x7fffu + ((x.u >> 16) & 1u);
  return (uint16_t)(r >> 16);
}

static __device__ __forceinline__ uint32_t cvtpk_bf16(float lo, float hi) {
  uint32_t r;
  asm("v_cvt_pk_bf16_f32 %0, %1, %2" : "=v"(r) : "v"(lo), "v"(hi));
  return r;
}

constexpr int DM = 1024, NH = 16, KD = 64, NB = 2, SQ = 2048;
constexpr int MTOT = NB * SQ;  // 4096
constexpr int NT = SQ / 64;    // 32 kv tiles
constexpr int NP = NT / 2;     // 16 kv pairs

// ---------------- kernel 1: fp32 -> bf16 convert ----------------
__global__ void convert_kernel(const float* __restrict__ X,
                               const float* __restrict__ Wq, const float* __restrict__ Wk,
                               const float* __restrict__ Wv, const float* __restrict__ Wo,
                               uint16_t* __restrict__ Xb, uint16_t* __restrict__ Wqkvb,
                               uint16_t* __restrict__ Wob) {
  const int NX = MTOT * DM;   // 4194304
  const int NW = DM * DM;     // 1048576
  const int TOT8 = (NX + 4 * NW) / 8;
  for (int t = blockIdx.x * blockDim.x + threadIdx.x; t < TOT8; t += gridDim.x * blockDim.x) {
    int i = t * 8;
    const float* src; uint16_t* dst;
    if (i < NX) { src = X + i; dst = Xb + i; }
    else if (i < NX + 3 * NW) {
      int j = i - NX; dst = Wqkvb + j;
      src = (j < NW) ? (Wq + j) : (j < 2 * NW) ? (Wk + (j - NW)) : (Wv + (j - 2 * NW));
    } else {
      int j = i - NX - 3 * NW; src = Wo + j; dst = Wob + j;
    }
    float4 a = ((const float4*)src)[0];
    float4 b = ((const float4*)src)[1];
    ushort4 o0, o1;
    o0.x = f2bf(a.x); o0.y = f2bf(a.y); o0.z = f2bf(a.z); o0.w = f2bf(a.w);
    o1.x = f2bf(b.x); o1.y = f2bf(b.y); o1.z = f2bf(b.z); o1.w = f2bf(b.w);
    ((ushort4*)dst)[0] = o0;
    ((ushort4*)dst)[1] = o1;
  }
}

// ---------------- kernel 2: 128x128 bf16 GEMM, C = A @ B^T (QKV) — R10 proven version ------
__global__ __launch_bounds__(256) void gemm_qkv(const uint16_t* __restrict__ Aq,
                                                const uint16_t* __restrict__ Bq,
                                                uint16_t* __restrict__ Qb, uint16_t* __restrict__ Kb,
                                                uint16_t* __restrict__ VTb) {
  __shared__ uint16_t Al[128 * 32];
  __shared__ uint16_t Bl[128 * 32];
  const int K = 1024;
  const int Ntiles = 24;
  int nwg = gridDim.x;
  int bid = (blockIdx.x & 7) * (nwg >> 3) + (blockIdx.x >> 3);
  int bm = bid / Ntiles, bn = bid % Ntiles;
  int brow = bm * 128, bcol = bn * 128;
  int tid = threadIdx.x;
  int w = tid >> 6, lane = tid & 63, g = lane >> 4, c16 = lane & 15;
  int wm = w >> 1, wn = w & 1;
  int rr = tid >> 2;            // 0..63 row within 64-row half-tile
  int ce = (tid & 3) * 8;       // col element (8 bf16 = 16B)

  floatx4 acc[4][4] = {};

  for (int k0 = 0; k0 < K; k0 += 32) {
    __syncthreads();
#pragma unroll
    for (int c = 0; c < 2; ++c) {
      __builtin_amdgcn_global_load_lds(
          (const __attribute__((address_space(1))) void*)(Aq + (size_t)(brow + c * 64 + rr) * K + k0 + ce),
          (__attribute__((address_space(3))) void*)((char*)Al + c * 4096 + w * 1024), 16, 0, 0);
      __builtin_amdgcn_global_load_lds(
          (const __attribute__((address_space(1))) void*)(Bq + (size_t)(bcol + c * 64 + rr) * K + k0 + ce),
          (__attribute__((address_space(3))) void*)((char*)Bl + c * 4096 + w * 1024), 16, 0, 0);
    }
    __syncthreads();
    short8 af[4], bf[4];
#pragma unroll
    for (int mt = 0; mt < 4; ++mt)
      af[mt] = *(const short8*)&Al[(wm * 64 + mt * 16 + c16) * 32 + g * 8];
#pragma unroll
    for (int nt = 0; nt < 4; ++nt)
      bf[nt] = *(const short8*)&Bl[(wn * 64 + nt * 16 + c16) * 32 + g * 8];
#pragma unroll
    for (int mt = 0; mt < 4; ++mt)
#pragma unroll
      for (int nt = 0; nt < 4; ++nt)
        acc[mt][nt] = MFMA16(af[mt], bf[nt], acc[mt][nt]);
  }

#pragma unroll
  for (int mt = 0; mt < 4; ++mt) {
#pragma unroll
    for (int nt = 0; nt < 4; ++nt) {
      int n = bcol + wn * 64 + nt * 16 + c16;
#pragma unroll
      for (int r = 0; r < 4; ++r) {
        int m = brow + wm * 64 + mt * 16 + g * 4 + r;
        float v = acc[mt][nt][r];
        int proj = n >> 10;
        int hd = n & 1023;
        int h = hd >> 6, d = hd & 63;
        int b = m >> 11, s = m & 2047;
        size_t bh = (size_t)(b * NH + h);
        if (proj == 0) {
          // fold 1/sqrt(64) * log2(e) so attention can use exp2 directly
          Qb[(bh * SQ + s) * KD + d] = f2bf(v * 0.18033688011112042f);
        } else if (proj == 1) {
          // K blocked frag-linear: elem = st*1024 + k8*128 + r2*8 + j
          int st = s >> 4, r2 = s & 15, k8 = d >> 3, j = d & 7;
          Kb[bh * (size_t)(SQ * KD) + (((size_t)(st * 8 + k8) * 16 + r2) * 8 + j)] = f2bf(v);
        } else {
          // V pi-permuted blocked per 64-kv tile
          int kt = s >> 6, kvl = s & 63;
          int c = kvl >> 5, tth = (kvl >> 4) & 1, gg = (kvl >> 2) & 3, rs = kvl & 3;
          int jp = tth * 4 + rs;
          int dt = d >> 4, cc = d & 15;
          VTb[bh * (size_t)(SQ * KD) + (size_t)kt * 4096 +
              (size_t)((c * 4 + dt) * 512 + gg * 128 + cc * 8 + jp)] = f2bf(v);
        }
      }
    }
  }
}

// ---------------- kernel 4: 64x128 bf16 GEMM, Out = Ob @ Wo^T — R10 proven version --------
__global__ __launch_bounds__(256) void gemm_out64(const uint16_t* __restrict__ Aq,
                                                  const uint16_t* __restrict__ Bq,
                                                  float* __restrict__ Out) {
  __shared__ uint16_t Al[64 * 32];
  __shared__ uint16_t Bl[128 * 32];
  const int K = 1024;
  int nwg = gridDim.x;  // 512
  int bid = (blockIdx.x & 7) * (nwg >> 3) + (blockIdx.x >> 3);
  int bm = bid >> 3, bn = bid & 7;   // 64 x 8 tiles
  int brow = bm * 64, bcol = bn * 128;
  int tid = threadIdx.x;
  int w = tid >> 6, lane = tid & 63, g = lane >> 4, c16 = lane & 15;
  int wm = w >> 1, wn = w & 1;       // wave-tile: 32 rows x 64 cols
  int rr = tid >> 2;
  int ce = (tid & 3) * 8;

  floatx4 acc[2][4] = {};

  for (int k0 = 0; k0 < K; k0 += 32) {
    __syncthreads();
    __builtin_amdgcn_global_load_lds(
        (const __attribute__((address_space(1))) void*)(Aq + (size_t)(brow + rr) * K + k0 + ce),
        (__attribute__((address_space(3))) void*)((char*)Al + w * 1024), 16, 0, 0);
#pragma unroll
    for (int c = 0; c < 2; ++c) {
      __builtin_amdgcn_global_load_lds(
          (const __attribute__((address_space(1))) void*)(Bq + (size_t)(bcol + c * 64 + rr) * K + k0 + ce),
          (__attribute__((address_space(3))) void*)((char*)Bl + c * 4096 + w * 1024), 16, 0, 0);
    }
    __syncthreads();
    short8 af[2], bf[4];
#pragma unroll
    for (int mt = 0; mt < 2; ++mt)
      af[mt] = *(const short8*)&Al[(wm * 32 + mt * 16 + c16) * 32 + g * 8];
#pragma unroll
    for (int nt = 0; nt < 4; ++nt)
      bf[nt] = *(const short8*)&Bl[(wn * 64 + nt * 16 + c16) * 32 + g * 8];
#pragma unroll
    for (int mt = 0; mt < 2; ++mt)
#pragma unroll
      for (int nt = 0; nt < 4; ++nt)
        acc[mt][nt] = MFMA16(af[mt], bf[nt], acc[mt][nt]);
  }

#pragma unroll
  for (int mt = 0; mt < 2; ++mt) {
#pragma unroll
    for (int nt = 0; nt < 4; ++nt) {
      int n = bcol + wn * 64 + nt * 16 + c16;
#pragma unroll
      for (int r = 0; r < 4; ++r) {
        int m = brow + wm * 32 + mt * 16 + g * 4 + r;
        Out[(size_t)m * DM + n] = acc[mt][nt][r];
      }
    }
  }
}

// ---------------- kernel 3: flash attention, MFMA-computed l (ones-column trick) ----------
// l = P @ ones via MFMA: D-layout puts l for q-row g*4+r in lacc[r] — the SAME mapping as
// accO[dt][r], so normalization is lane-local (no shuffles). Removes 19 VALU adds/sub-tile
// + the final cross-lane reduce; moves the sum to the 23%-utilized MFMA pipe (+2 MFMA).
// l now sums the same bf16-rounded P used in PV (self-consistent normalization).
__global__ __launch_bounds__(512, 4) void attn_kernel(const uint16_t* __restrict__ Q,
                                                      const uint16_t* __restrict__ Kt,
                                                      const uint16_t* __restrict__ Vt,
                                                      uint16_t* __restrict__ O) {
  __shared__ __attribute__((aligned(16))) uint16_t Kbuf[2][8192];  // 2 x 16KB (tile pair)
  __shared__ __attribute__((aligned(16))) uint16_t Vbuf[2][8192];  // 2 x 16KB

  int bid = blockIdx.x;
  int bh = bid & 31, qt = bid >> 5;    // 32 bh x 16 q-tiles = 512 blocks
  int qb = qt * 128;
  int b = bh >> 4, h = bh & 15;
  int tid = threadIdx.x, lane = tid & 63, wv = tid >> 6, g = lane >> 4, c16 = lane & 15;

  const uint16_t* Qh = Q + (size_t)bh * SQ * KD;
  const uint16_t* Kh = Kt + (size_t)bh * SQ * KD;
  const uint16_t* Vh = Vt + (size_t)bh * SQ * KD;

  int qrow = qb + wv * 16 + c16;
  short8 qf0 = *(const short8*)&Qh[(size_t)qrow * KD + g * 8];
  short8 qf1 = *(const short8*)&Qh[(size_t)qrow * KD + 32 + g * 8];

  floatx4 accO[4] = {};
  floatx4 lacc = {};                    // l via MFMA: lacc[r] = sum_k P[q=g*4+r][k]
  const floatx4 SHIFT_INIT = {-16.0f, -16.0f, -16.0f, -16.0f};

  union { uint32_t u[4]; short8 s8; } onesf;
#pragma unroll
  for (int i = 0; i < 4; ++i) onesf.u[i] = 0x3F803F80u;  // bf16 1.0 pairs

  auto stage = [&](int buf, int pair) {
    size_t base = (size_t)pair * 8192;
#pragma unroll
    for (int i = 0; i < 2; ++i) {
      __builtin_amdgcn_global_load_lds(
          (const __attribute__((address_space(1))) void*)(Kh + base + wv * 1024 + i * 512 + lane * 8),
          (__attribute__((address_space(3))) void*)((char*)&Kbuf[buf][0] + wv * 2048 + i * 1024), 16, 0, 0);
      __builtin_amdgcn_global_load_lds(
          (const __attribute__((address_space(1))) void*)(Vh + base + wv * 1024 + i * 512 + lane * 8),
          (__attribute__((address_space(3))) void*)((char*)&Vbuf[buf][0] + wv * 2048 + i * 1024), 16, 0, 0);
    }
  };

  stage(0, 0);
  __syncthreads();

  for (int p = 0; p < NP; ++p) {
    int cur = p & 1;
    int pn = (p + 1 < NP) ? (p + 1) : p;
    stage(cur ^ 1, pn);   // issue next-pair loads FIRST; they fly over this pair's compute

#pragma unroll
    for (int sub = 0; sub < 2; ++sub) {
      const char* kb = (const char*)&Kbuf[cur][sub * 4096];
      const char* vb = (const char*)&Vbuf[cur][sub * 4096];
      short8 kf[4][2], vf[2][4];
#pragma unroll
      for (int tt = 0; tt < 4; ++tt)
#pragma unroll
        for (int hf = 0; hf < 2; ++hf)
          kf[tt][hf] = *(const short8*)(kb + tt * 2048 + hf * 1024 + lane * 16);
#pragma unroll
      for (int c = 0; c < 2; ++c)
#pragma unroll
        for (int dt = 0; dt < 4; ++dt)
          vf[c][dt] = *(const short8*)(vb + (c * 4 + dt) * 1024 + lane * 16);

      // ---- S^T - 16 = K @ Q^T + (-16) : lane (c16 = q) holds kv = tt*16 + g*4 + r ----
      floatx4 sacc[4];
#pragma unroll
      for (int tt = 0; tt < 4; ++tt) sacc[tt] = SHIFT_INIT;
      __builtin_amdgcn_s_setprio(1);
#pragma unroll
      for (int tt = 0; tt < 4; ++tt) {
        sacc[tt] = MFMA16(kf[tt][0], qf0, sacc[tt]);
        sacc[tt] = MFMA16(kf[tt][1], qf1, sacc[tt]);
      }
      __builtin_amdgcn_s_setprio(0);

      // ---- P = 2^(s-16) (no max, no branch, no rescale, no VALU sum) ----
#pragma unroll
      for (int tt = 0; tt < 4; ++tt)
#pragma unroll
        for (int r = 0; r < 4; ++r)
          sacc[tt][r] = exp2f(sacc[tt][r]);

      // ---- P pack (pure-local thanks to pi-permuted V) + PV + l-via-MFMA ----
      union { uint32_t u[4]; short8 s8; } pa[2];
#pragma unroll
      for (int c = 0; c < 2; ++c) {
        pa[c].u[0] = cvtpk_bf16(sacc[2 * c][0], sacc[2 * c][1]);
        pa[c].u[1] = cvtpk_bf16(sacc[2 * c][2], sacc[2 * c][3]);
        pa[c].u[2] = cvtpk_bf16(sacc[2 * c + 1][0], sacc[2 * c + 1][1]);
        pa[c].u[3] = cvtpk_bf16(sacc[2 * c + 1][2], sacc[2 * c + 1][3]);
      }
      __builtin_amdgcn_s_setprio(1);
#pragma unroll
      for (int c = 0; c < 2; ++c) {
#pragma unroll
        for (int dt = 0; dt < 4; ++dt)
          accO[dt] = MFMA16(pa[c].s8, vf[c][dt], accO[dt]);
        lacc = MFMA16(pa[c].s8, onesf.s8, lacc);   // row-sum of P on the MFMA pipe
      }
      __builtin_amdgcn_s_setprio(0);
    }

    __syncthreads();  // drains stage vmcnt + all waves done reading buf[cur]
  }

  // ---- normalize (lane-local: lacc[r] matches accO[.][r] row mapping) + store ----
  float lv[4];
#pragma unroll
  for (int r = 0; r < 4; ++r) lv[r] = 1.0f / lacc[r];
#pragma unroll
  for (int dt = 0; dt < 4; ++dt) {
#pragma unroll
    for (int r = 0; r < 4; ++r) {
      int s = qb + wv * 16 + g * 4 + r;
      int d = dt * 16 + c16;
      O[((size_t)(b * SQ + s)) * DM + h * KD + d] = f2bf(accO[dt][r] * lv[r]);
    }
  }
}

// ---------------- launch ----------------
extern "C" void kernel_launch(void* const* d_in, const int* in_sizes, int n_in,
                              void* d_out, int out_size, void* d_ws, size_t ws_size,
                              hipStream_t stream) {
  const float* X = (const float*)d_in[0];
  const float* Wq = (const float*)d_in[1];
  const float* Wk = (const float*)d_in[2];
  const float* Wv = (const float*)d_in[3];
  const float* Wo = (const float*)d_in[4];
  float* out = (float*)d_out;

  char* ws = (char*)d_ws;
  uint16_t* Xb    = (uint16_t*)(ws);                 //  8 MiB  [4096][1024]
  uint16_t* Wqkvb = (uint16_t*)(ws + 8388608);       //  6 MiB  [3072][1024]
  uint16_t* Wob   = (uint16_t*)(ws + 14680064);      //  2 MiB  [1024][1024]
  uint16_t* Qb    = (uint16_t*)(ws + 16777216);      //  8 MiB  (bh,s,d)
  uint16_t* Kb    = (uint16_t*)(ws + 25165824);      //  8 MiB  blocked
  uint16_t* VTb   = (uint16_t*)(ws + 33554432);      //  8 MiB  pi-permuted blocked
  uint16_t* Ob    = (uint16_t*)(ws + 41943040);      //  8 MiB  [4096][1024]

  hipLaunchKernelGGL(convert_kernel, dim3(1024), dim3(256), 0, stream,
                     X, Wq, Wk, Wv, Wo, Xb, Wqkvb, Wob);
  hipLaunchKernelGGL(gemm_qkv, dim3(32 * 24), dim3(256), 0, stream,
                     Xb, Wqkvb, Qb, Kb, VTb);
  hipLaunchKernelGGL(attn_kernel, dim3(512), dim3(512), 0, stream,
                     Qb, Kb, VTb, Ob);
  hipLaunchKernelGGL(gemm_out64, dim3(512), dim3(256), 0, stream,
                     Ob, Wob, out);
}